// Round 8
// baseline (1023.561 us; speedup 1.0000x reference)
//
#include <hip/hip_runtime.h>
#include <hip/hip_cooperative_groups.h>
#include <math.h>

namespace cg = cooperative_groups;

#define NN 100000
#define NE 1600000
#define ET (NE + NN)            // 1,700,000 edges incl. self-loops
#define NEG 0.2f
#define KP 192                  // padded K for MFMA (165 -> 192)
#define GEMM_BLKS (NN / 32)     // 3125
#define SLOTS 64                // fixed edge slots per node (P(deg>63) ~ 1e-25)
#define NPART 8                 // dst-range partitions (R6 histscat)
#define PART_SZ (NN / NPART)    // 12500
#define NCHUNK 1024
#define CH ((NE + NCHUNK - 1) / NCHUNK)   // 1563 edges per chunk

typedef __attribute__((ext_vector_type(8))) short short8;
typedef __attribute__((ext_vector_type(4))) float floatx4;

// bf16 helpers (round-to-nearest-even)
__device__ __forceinline__ unsigned short f2bf(float f) {
    unsigned u = __float_as_uint(f);
    unsigned r = u + 0x7fffu + ((u >> 16) & 1u);
    return (unsigned short)(r >> 16);
}
__device__ __forceinline__ float bflo(unsigned x) { return __uint_as_float(x << 16); }
__device__ __forceinline__ float bfhi(unsigned x) { return __uint_as_float(x & 0xFFFF0000u); }

// =============================================================================
// R8: single cooperative mega-kernel. 5 phases separated by grid.sync().
// Rationale: R5 (+3 launches = +45us) and R7 (+1 launch = +8us) show ~10-15us
// per serialized dispatch; 5->1 launches reclaims ~40-60us of gap time.
// __launch_bounds__(256,6): 6 blocks/CU guaranteed (l1agg needs ~75%+ occ;
// VGPR cap 84 expected to hold gemm1's ~80-reg live set without spill).
// =============================================================================
__global__ __launch_bounds__(256, 6) void k_mega(
    const float* __restrict__ W1, const float* __restrict__ x,
    const int* __restrict__ src, const int* __restrict__ dst,
    const float* __restrict__ as1, const float* __restrict__ ad1,
    const float* __restrict__ b1, const float* __restrict__ W2,
    const float* __restrict__ as2, const float* __restrict__ ad2,
    const float* __restrict__ b2,
    unsigned short* __restrict__ Wt, unsigned* __restrict__ xbf32,
    int* __restrict__ deg, int* __restrict__ esrc,
    unsigned short* __restrict__ h1, float* __restrict__ a_src,
    float* __restrict__ a_dst, float4* __restrict__ node2,
    float* __restrict__ out)
{
    __shared__ __align__(16) unsigned lds_p[32 * 132];   // 16.9 KB (gemm1 epilogue)
    cg::grid_group grid = cg::this_grid();
    const int t = threadIdx.x;

    // ---------------- phase 1: prep (Wt bf16, deg=1 + self-loop, xbf) --------
    {
        const int gid = blockIdx.x * 256 + t;
        const int G = gridDim.x * 256;
        for (int idx = gid; idx < 256 * KP; idx += G) {
            const int n = idx / KP, k = idx - n * KP;
            Wt[idx] = (k < 165) ? f2bf(W1[k * 256 + n]) : (unsigned short)0;
        }
        for (int i = gid; i < NN; i += G) { deg[i] = 1; esrc[i << 6] = i; }
        for (int p = gid; p < NN * (KP / 2); p += G) {
            const int n = p / (KP / 2), i = p - n * (KP / 2);
            const int k0 = 2 * i;
            const float v0 = (k0 < 165) ? x[(size_t)n * 165 + k0] : 0.0f;
            const float v1 = (k0 + 1 < 165) ? x[(size_t)n * 165 + k0 + 1] : 0.0f;
            xbf32[p] = (unsigned)f2bf(v0) | ((unsigned)f2bf(v1) << 16);
        }
    }
    grid.sync();

    // ---------------- phase 2: hist+scatter (R6 dst-partitioned) -------------
    {
        for (int b = blockIdx.x; b < NPART * NCHUNK; b += gridDim.x) {
            const int p = b & 7;
            const int chunk = b >> 3;
            const int e0 = chunk * CH;
            const int e1 = (e0 + CH < NE) ? e0 + CH : NE;
            const int plo = p * PART_SZ, phi = plo + PART_SZ;
            for (int e = e0 + t; e < e1; e += 256) {
                const int d = dst[e];
                if (d >= plo && d < phi) {
                    const int s = src[e];
                    const int r = atomicAdd(&deg[d], 1);
                    if (r < SLOTS) esrc[(d << 6) + r] = s;
                }
            }
        }
    }
    grid.sync();

    // ---------------- phase 3: GEMM1 via MFMA (h1 = xbf @ W1 -> bf16) --------
    {
        const unsigned short* xbf = (const unsigned short*)xbf32;
        const int lane = t & 63, hd = t >> 6;
        const int r16 = lane & 15, quad = lane >> 4;
        float asw[4], adw[4];
#pragma unroll
        for (int nn = 0; nn < 4; ++nn) {
            asw[nn] = as1[hd * 64 + nn * 16 + r16];
            adw[nn] = ad1[hd * 64 + nn * 16 + r16];
        }
        for (int tb = blockIdx.x; tb < GEMM_BLKS; tb += gridDim.x) {
            __syncthreads();                      // protect lds_p reuse across tiles
            const int n0 = tb * 32;
            floatx4 zero4 = {0.0f, 0.0f, 0.0f, 0.0f};
            floatx4 acc[2][4];
#pragma unroll
            for (int mm = 0; mm < 2; ++mm)
#pragma unroll
                for (int nn = 0; nn < 4; ++nn) acc[mm][nn] = zero4;

            const unsigned short* xr0 = xbf + (size_t)(n0 + r16) * KP;
            const unsigned short* xr1 = xbf + (size_t)(n0 + 16 + r16) * KP;
#pragma unroll
            for (int ks = 0; ks < 6; ++ks) {
                const int kb = ks * 32 + quad * 8;
                short8 a0 = *(const short8*)(xr0 + kb);
                short8 a1 = *(const short8*)(xr1 + kb);
                short8 bfv[4];
#pragma unroll
                for (int nn = 0; nn < 4; ++nn)
                    bfv[nn] = *(const short8*)(Wt + (size_t)(hd * 64 + nn * 16 + r16) * KP + kb);
#pragma unroll
                for (int nn = 0; nn < 4; ++nn) {
                    acc[0][nn] = __builtin_amdgcn_mfma_f32_16x16x32_bf16(a0, bfv[nn], acc[0][nn], 0, 0, 0);
                    acc[1][nn] = __builtin_amdgcn_mfma_f32_16x16x32_bf16(a1, bfv[nn], acc[1][nn], 0, 0, 0);
                }
            }

#pragma unroll
            for (int mm = 0; mm < 2; ++mm)
#pragma unroll
                for (int r = 0; r < 4; ++r) {
                    float ps = acc[mm][0][r] * asw[0] + acc[mm][1][r] * asw[1] +
                               acc[mm][2][r] * asw[2] + acc[mm][3][r] * asw[3];
                    float pd = acc[mm][0][r] * adw[0] + acc[mm][1][r] * adw[1] +
                               acc[mm][2][r] * adw[2] + acc[mm][3][r] * adw[3];
                    ps += __shfl_xor(ps, 1); ps += __shfl_xor(ps, 2);
                    ps += __shfl_xor(ps, 4); ps += __shfl_xor(ps, 8);
                    pd += __shfl_xor(pd, 1); pd += __shfl_xor(pd, 2);
                    pd += __shfl_xor(pd, 4); pd += __shfl_xor(pd, 8);
                    if (r16 == 0) {
                        const int node = n0 + mm * 16 + quad * 4 + r;
                        a_src[node * 4 + hd] = ps;
                        a_dst[node * 4 + hd] = pd;
                    }
                }

#pragma unroll
            for (int mm = 0; mm < 2; ++mm)
#pragma unroll
                for (int nn = 0; nn < 4; ++nn)
#pragma unroll
                    for (int r = 0; r < 4; ++r) {
                        const float v = acc[mm][nn][r];
                        const float o = __shfl_xor(v, 1);
                        if ((lane & 1) == 0) {
                            const unsigned pk = (unsigned)f2bf(v) | ((unsigned)f2bf(o) << 16);
                            lds_p[(mm * 16 + quad * 4 + r) * 132 + hd * 32 + nn * 8 + (r16 >> 1)] = pk;
                        }
                    }
            __syncthreads();
            {
                const int row = t & 31, seg = t >> 5;
                const unsigned* p = &lds_p[row * 132 + seg * 16];
                uint4 d0 = *(const uint4*)(p);
                uint4 d1 = *(const uint4*)(p + 4);
                uint4 d2 = *(const uint4*)(p + 8);
                uint4 d3 = *(const uint4*)(p + 12);
                unsigned short* hp = h1 + (size_t)(n0 + row) * 256 + seg * 32;
                *(uint4*)(hp) = d0;
                *(uint4*)(hp + 8) = d1;
                *(uint4*)(hp + 16) = d2;
                *(uint4*)(hp + 24) = d3;
            }
        }
    }
    grid.sync();

    // ---------------- phase 4: layer-1 aggregation ---------------------------
    // (R1/R2 lessons preserved: 32-VGPR guarded schedule, TLP does the hiding)
    {
        const int l = t & 63;
        const int q = l >> 4;
        const int sl = l & 15;
        const int head = sl >> 2;
        const int c0 = sl * 16;
        const int el = l >> 2;
        const int hl = l & 3;
        for (int nb = blockIdx.x; nb < NN / 4; nb += gridDim.x) {
            const int n = nb * 4 + (t >> 6);
            const int dg = deg[n];
            const int ebase = n << 6;
            const float4 ad4 = *(const float4*)&a_dst[n * 4];
            const float adh = (hl == 0) ? ad4.x : (hl == 1) ? ad4.y : (hl == 2) ? ad4.z : ad4.w;

            float ssum = 0.0f;
            float acc[16];
#pragma unroll
            for (int c = 0; c < 16; ++c) acc[c] = 0.0f;

            for (int base = 0; base < dg; base += 16) {
                const int cnt = dg - base;
                const int iters = (cnt < 16) ? cnt : 16;
                int sA = 0; float pA = 0.0f;
                if (el < cnt) {
                    sA = esrc[ebase + base + el];
                    const float a = a_src[sA * 4 + hl] + adh;
                    const float e = (a > 0.0f) ? a : NEG * a;
                    pA = __expf(e);
                }
#pragma unroll
                for (int jb = 0; jb < 16; jb += 4) {
                    const int j = jb + q;
                    const int s = __shfl(sA, j << 2);
                    const float p = __shfl(pA, (j << 2) | head);
                    if (j < iters) {
                        ssum += p;
                        const unsigned ho = ((unsigned)s << 8) + c0;
                        const uint4 hv0 = *(const uint4*)(h1 + ho);
                        const uint4 hv1 = *(const uint4*)(h1 + ho + 8);
                        acc[0]  += p * bflo(hv0.x); acc[1]  += p * bfhi(hv0.x);
                        acc[2]  += p * bflo(hv0.y); acc[3]  += p * bfhi(hv0.y);
                        acc[4]  += p * bflo(hv0.z); acc[5]  += p * bfhi(hv0.z);
                        acc[6]  += p * bflo(hv0.w); acc[7]  += p * bfhi(hv0.w);
                        acc[8]  += p * bflo(hv1.x); acc[9]  += p * bfhi(hv1.x);
                        acc[10] += p * bflo(hv1.y); acc[11] += p * bfhi(hv1.y);
                        acc[12] += p * bflo(hv1.z); acc[13] += p * bfhi(hv1.z);
                        acc[14] += p * bflo(hv1.w); acc[15] += p * bfhi(hv1.w);
                    }
                }
            }
            ssum += __shfl_xor(ssum, 16); ssum += __shfl_xor(ssum, 32);
#pragma unroll
            for (int c = 0; c < 16; ++c) {
                acc[c] += __shfl_xor(acc[c], 16);
                acc[c] += __shfl_xor(acc[c], 32);
            }
            const float inv = 1.0f / ssum;
            float p0 = 0.0f, p1 = 0.0f;
#pragma unroll
            for (int c = 0; c < 16; ++c) {
                const float v = fmaxf(acc[c] * inv + b1[c0 + c], 0.0f);
                p0 += v * W2[(c0 + c) * 2 + 0];
                p1 += v * W2[(c0 + c) * 2 + 1];
            }
            if (q) { p0 = 0.0f; p1 = 0.0f; }
#pragma unroll
            for (int off = 32; off; off >>= 1) {
                p0 += __shfl_down(p0, off);
                p1 += __shfl_down(p1, off);
            }
            if (l == 0) {
                const float as2v = p0 * as2[0] + p1 * as2[1];
                const float ad2v = p0 * ad2[0] + p1 * ad2[1];
                node2[n] = make_float4(p0, p1, as2v, ad2v);
            }
        }
    }
    grid.sync();

    // ---------------- phase 5: layer-2 aggregation + log_softmax -------------
    {
        const int l = t & 63;
        const int g = l >> 4;
        const int i = l & 15;
        for (int nb = blockIdx.x; nb < NN / 16; nb += gridDim.x) {
            const int n = nb * 16 + (t >> 6) * 4 + g;
            const int dg = deg[n];
            const int ebase = n << 6;
            const float adst = node2[n].w;
            float ssum = 0.0f, a0 = 0.0f, a1 = 0.0f;
            for (int idx = i; idx < dg; idx += 16) {
                const int s = esrc[ebase + idx];
                const float4 r = node2[s];
                const float a = r.z + adst;
                const float e = (a > 0.0f) ? a : NEG * a;
                const float p = __expf(e);
                ssum += p; a0 += p * r.x; a1 += p * r.y;
            }
#pragma unroll
            for (int off = 8; off; off >>= 1) {
                ssum += __shfl_xor(ssum, off);
                a0 += __shfl_xor(a0, off);
                a1 += __shfl_xor(a1, off);
            }
            if (i == 0) {
                const float inv = 1.0f / ssum;
                const float z0 = a0 * inv + b2[0];
                const float z1 = a1 * inv + b2[1];
                const float mz = fmaxf(z0, z1);
                const float lse = mz + __logf(__expf(z0 - mz) + __expf(z1 - mz));
                out[n * 2 + 0] = z0 - lse;
                out[n * 2 + 1] = z1 - lse;
            }
        }
    }
}

extern "C" void kernel_launch(void* const* d_in, const int* in_sizes, int n_in,
                              void* d_out, int out_size, void* d_ws, size_t ws_size,
                              hipStream_t stream) {
    const float* x    = (const float*)d_in[0];
    const int*   src  = (const int*)d_in[1];
    const int*   dst  = (const int*)d_in[2];
    const float* W1   = (const float*)d_in[3];
    const float* as1w = (const float*)d_in[4];
    const float* ad1w = (const float*)d_in[5];
    const float* b1   = (const float*)d_in[6];
    const float* W2   = (const float*)d_in[7];
    const float* as2w = (const float*)d_in[8];
    const float* ad2w = (const float*)d_in[9];
    const float* b2   = (const float*)d_in[10];
    float* out = (float*)d_out;

    char* w = (char*)d_ws;
    unsigned short* h1  = (unsigned short*)w; w += (size_t)NN * 256 * 2;  // 51.2 MB
    unsigned short* Wt  = (unsigned short*)w; w += (size_t)256 * KP * 2;  // 98 KB
    unsigned* xbf32     = (unsigned*)w;       w += (size_t)NN * KP * 2;   // 38.4 MB
    float* a_src = (float*)w; w += (size_t)NN * 4 * 4;
    float* a_dst = (float*)w; w += (size_t)NN * 4 * 4;
    float4* node2 = (float4*)w; w += (size_t)NN * 4 * 4;
    int* deg     = (int*)w;   w += (size_t)NN * 4;
    int* esrc    = (int*)w;   w += (size_t)NN * SLOTS * 4;                // 25.6 MB

    // co-residency-safe grid: query actual occupancy (pure query; capture-safe)
    int maxb = 0;
    (void)hipOccupancyMaxActiveBlocksPerMultiprocessor(&maxb, (const void*)k_mega, 256, 0);
    if (maxb < 1) maxb = 1;
    if (maxb > 8) maxb = 8;
    dim3 grid(256 * maxb);

    void* args[] = {
        (void*)&W1, (void*)&x, (void*)&src, (void*)&dst,
        (void*)&as1w, (void*)&ad1w, (void*)&b1, (void*)&W2,
        (void*)&as2w, (void*)&ad2w, (void*)&b2,
        (void*)&Wt, (void*)&xbf32, (void*)&deg, (void*)&esrc,
        (void*)&h1, (void*)&a_src, (void*)&a_dst, (void*)&node2, (void*)&out };
    hipLaunchCooperativeKernel((void*)k_mega, grid, dim3(256), args, 0, stream);
}

// Round 9
// 424.490 us; speedup vs baseline: 2.4113x; 2.4113x over previous
//
#include <hip/hip_runtime.h>
#include <math.h>

#define NN 100000
#define NE 1600000
#define ET (NE + NN)            // 1,700,000 edges incl. self-loops
#define NEG 0.2f
#define KP 192                  // padded K for MFMA (165 -> 192)
#define GEMM_BLKS (NN / 32)     // 3125
#define SLOTS 64                // fixed edge slots per node (P(deg>63) ~ 1e-25)
#define NPART 8                 // dst-range partitions (R6 histscat)
#define PART_SZ (NN / NPART)    // 12500
#define NCHUNK 1024
#define CH ((NE + NCHUNK - 1) / NCHUNK)   // 1563 edges per chunk
#define HS_BLKS (NPART * NCHUNK)          // 8192 histscat role blocks
#define LDA 200                 // LDS A-tile row stride in bf16 (400B: 16B-aligned rows,
                                // dword-bank step 100%32=4 -> 2 rows/bank = free)

typedef __attribute__((ext_vector_type(8))) short short8;
typedef __attribute__((ext_vector_type(4))) float floatx4;

// bf16 helpers (round-to-nearest-even)
__device__ __forceinline__ unsigned short f2bf(float f) {
    unsigned u = __float_as_uint(f);
    unsigned r = u + 0x7fffu + ((u >> 16) & 1u);
    return (unsigned short)(r >> 16);
}
__device__ __forceinline__ float bflo(unsigned x) { return __uint_as_float(x << 16); }
__device__ __forceinline__ float bfhi(unsigned x) { return __uint_as_float(x & 0xFFFF0000u); }

// ---------------- prep: Wt bf16 [256][KP], deg=1 + self-loop slot0 -----------
// R9: xbf pass deleted (gemm stages x directly via LDS); prep is now tiny.
__global__ __launch_bounds__(256) void k_prep(const float* __restrict__ W,
                                              unsigned short* __restrict__ Wt,
                                              int* __restrict__ deg,
                                              int* __restrict__ esrc) {
    const int gid = blockIdx.x * 256 + threadIdx.x;
    const int G = gridDim.x * 256;
    for (int idx = gid; idx < 256 * KP; idx += G) {
        const int n = idx / KP, k = idx - n * KP;
        Wt[idx] = (k < 165) ? f2bf(W[k * 256 + n]) : (unsigned short)0;
    }
    // self-loop pre-placed at slot 0: removes 100K edges from the scatter
    for (int i = gid; i < NN; i += G) { deg[i] = 1; esrc[i << 6] = i; }
}

// ---------------- fused histscat + GEMM1 (block-role split, R9) --------------
// Roles are disjoint and independent: blocks [0,HS_BLKS) run the R6 dst-
// partitioned edge-table build (latency/atomic-bound, 0.5% VALU); blocks
// [HS_BLKS, HS_BLKS+GEMM_BLKS) each compute one 32-node MFMA tile (compute/
// BW-bound). gemm backfills CU slots under the ~105us histscat long pole.
// NOT cooperative (R8 lesson: capped resident grid + grid.sync = 2.8x slower;
// oversubscribed block churn is itself a latency-hiding resource).
// GEMM A-path: stage 32 x-rows once, coalesced, f32->bf16 into LDS [32][LDA]
// (R4 lesson: per-lane redundant global f32 A-reads cost 35-40us; staging
// fixes redundancy AND alignment). h1 numerics bit-identical to xbf path.
__global__ __launch_bounds__(256) void k_hsgemm(const int* __restrict__ src,
                                                const int* __restrict__ dst,
                                                const float* __restrict__ x,
                                                const unsigned short* __restrict__ Wt,
                                                const float* __restrict__ att_s,
                                                const float* __restrict__ att_d,
                                                int* __restrict__ deg,
                                                int* __restrict__ esrc,
                                                unsigned short* __restrict__ h1,
                                                float* __restrict__ a_src,
                                                float* __restrict__ a_dst) {
    __shared__ __align__(16) unsigned lds_u32[32 * 132];   // 16.9 KB, dual-use
    const int t = threadIdx.x;
    const int b = blockIdx.x;

    if (b < HS_BLKS) {
        // ---- histscat role (R6 dst-range partitioned) ----
        const int p = b & 7;
        const int chunk = b >> 3;
        const int e0 = chunk * CH;
        const int e1 = (e0 + CH < NE) ? e0 + CH : NE;
        const int plo = p * PART_SZ, phi = plo + PART_SZ;
        for (int e = e0 + t; e < e1; e += 256) {
            const int d = dst[e];
            if (d >= plo && d < phi) {
                const int s = src[e];
                const int r = atomicAdd(&deg[d], 1);
                if (r < SLOTS) esrc[(d << 6) + r] = s;
            }
        }
        return;
    }

    // ---- gemm role: one 32-node tile ----
    const int n0 = (b - HS_BLKS) * 32;
    unsigned short* lds_a = (unsigned short*)lds_u32;      // [32][LDA] bf16 A-tile

    // stage x rows (source-linear, coalesced, convert once) + zero the K-pad
    for (int i = t; i < 32 * 165; i += 256) {
        const int n = i / 165, k = i - n * 165;
        lds_a[n * LDA + k] = f2bf(x[(size_t)(n0 + n) * 165 + k]);
    }
    for (int i = t; i < 32 * (LDA - 165); i += 256) {      // k = 165..LDA-1 -> 0
        const int n = i / (LDA - 165), k = 165 + (i - n * (LDA - 165));
        lds_a[n * LDA + k] = 0;
    }
    __syncthreads();

    const int lane = t & 63, hd = t >> 6;
    const int r16 = lane & 15, quad = lane >> 4;
    floatx4 zero4 = {0.0f, 0.0f, 0.0f, 0.0f};
    floatx4 acc[2][4];
#pragma unroll
    for (int mm = 0; mm < 2; ++mm)
#pragma unroll
        for (int nn = 0; nn < 4; ++nn) acc[mm][nn] = zero4;

    const unsigned short* ar0 = lds_a + r16 * LDA;
    const unsigned short* ar1 = lds_a + (16 + r16) * LDA;
#pragma unroll
    for (int ks = 0; ks < 6; ++ks) {
        const int kb = ks * 32 + quad * 8;
        short8 a0 = *(const short8*)(ar0 + kb);
        short8 a1 = *(const short8*)(ar1 + kb);
        short8 bfv[4];
#pragma unroll
        for (int nn = 0; nn < 4; ++nn)
            bfv[nn] = *(const short8*)(Wt + (size_t)(hd * 64 + nn * 16 + r16) * KP + kb);
#pragma unroll
        for (int nn = 0; nn < 4; ++nn) {
            acc[0][nn] = __builtin_amdgcn_mfma_f32_16x16x32_bf16(a0, bfv[nn], acc[0][nn], 0, 0, 0);
            acc[1][nn] = __builtin_amdgcn_mfma_f32_16x16x32_bf16(a1, bfv[nn], acc[1][nn], 0, 0, 0);
        }
    }

    float asw[4], adw[4];
#pragma unroll
    for (int nn = 0; nn < 4; ++nn) {
        asw[nn] = att_s[hd * 64 + nn * 16 + r16];
        adw[nn] = att_d[hd * 64 + nn * 16 + r16];
    }
#pragma unroll
    for (int mm = 0; mm < 2; ++mm)
#pragma unroll
        for (int r = 0; r < 4; ++r) {
            float ps = acc[mm][0][r] * asw[0] + acc[mm][1][r] * asw[1] +
                       acc[mm][2][r] * asw[2] + acc[mm][3][r] * asw[3];
            float pd = acc[mm][0][r] * adw[0] + acc[mm][1][r] * adw[1] +
                       acc[mm][2][r] * adw[2] + acc[mm][3][r] * adw[3];
            ps += __shfl_xor(ps, 1); ps += __shfl_xor(ps, 2);
            ps += __shfl_xor(ps, 4); ps += __shfl_xor(ps, 8);
            pd += __shfl_xor(pd, 1); pd += __shfl_xor(pd, 2);
            pd += __shfl_xor(pd, 4); pd += __shfl_xor(pd, 8);
            if (r16 == 0) {
                const int node = n0 + mm * 16 + quad * 4 + r;
                a_src[node * 4 + hd] = ps;
                a_dst[node * 4 + hd] = pd;
            }
        }

    __syncthreads();   // A-tile reads done; reuse lds_u32 for epilogue transpose
#pragma unroll
    for (int mm = 0; mm < 2; ++mm)
#pragma unroll
        for (int nn = 0; nn < 4; ++nn)
#pragma unroll
            for (int r = 0; r < 4; ++r) {
                const float v = acc[mm][nn][r];
                const float o = __shfl_xor(v, 1);
                if ((lane & 1) == 0) {
                    const unsigned pk = (unsigned)f2bf(v) | ((unsigned)f2bf(o) << 16);
                    lds_u32[(mm * 16 + quad * 4 + r) * 132 + hd * 32 + nn * 8 + (r16 >> 1)] = pk;
                }
            }
    __syncthreads();
    {
        const int row = t & 31, seg = t >> 5;
        const unsigned* p = &lds_u32[row * 132 + seg * 16];
        uint4 d0 = *(const uint4*)(p);
        uint4 d1 = *(const uint4*)(p + 4);
        uint4 d2 = *(const uint4*)(p + 8);
        uint4 d3 = *(const uint4*)(p + 12);
        unsigned short* hp = h1 + (size_t)(n0 + row) * 256 + seg * 32;
        *(uint4*)(hp) = d0;
        *(uint4*)(hp + 8) = d1;
        *(uint4*)(hp + 16) = d2;
        *(uint4*)(hp + 24) = d3;
    }
}

// ---------------- layer-1 aggregation ---------------------------------------
// wave per node; padded 64-slot edge table (beg = n<<6, cnt = deg[n]).
// 16-edge register-staged chunks; phase B fixed 16-slot fully-unrolled; shfl
// at uniform control flow only; epilogue fuses bias+ReLU+@W2+att2 scalars.
// NOTE (R1/R2 lessons): this 32-VGPR guarded schedule is a measured local
// optimum. Hand-batched gathers (+24 VGPR) -> occupancy 78->40%, slower.
// Unguarded loads + __launch_bounds__(256,8) -> acc[] spill (555 MB scratch
// writes), 2x slower. TLP is doing the latency hiding; leave the guard alone.
// R5: 4-way grid split costs ~45us -> single launch. R8: cooperative mega-
// kernel (capped resident grid) -> 2.8x slower; keep standalone.
__global__ __launch_bounds__(256) void k_l1agg(const unsigned short* __restrict__ h1,
                                               const float* __restrict__ a_src,
                                               const float* __restrict__ a_dst,
                                               const int* __restrict__ deg,
                                               const int* __restrict__ esrc,
                                               const float* __restrict__ b1,
                                               const float* __restrict__ W2,
                                               const float* __restrict__ att_s2,
                                               const float* __restrict__ att_d2,
                                               float4* __restrict__ node2) {
    const int t = threadIdx.x;
    const int n = blockIdx.x * 4 + (t >> 6);
    const int l = t & 63;
    const int q = l >> 4;       // quarter 0..3 (phase B)
    const int sl = l & 15;      // lane in quarter
    const int head = sl >> 2;
    const int c0 = sl * 16;
    const int el = l >> 2;      // phase-A edge slot 0..15
    const int hl = l & 3;       // phase-A head
    const int dg = deg[n];
    const int ebase = n << 6;
    const float4 ad4 = *(const float4*)&a_dst[n * 4];
    const float adh = (hl == 0) ? ad4.x : (hl == 1) ? ad4.y : (hl == 2) ? ad4.z : ad4.w;

    float ssum = 0.0f;
    float acc[16];
#pragma unroll
    for (int c = 0; c < 16; ++c) acc[c] = 0.0f;

    for (int base = 0; base < dg; base += 16) {
        const int cnt = dg - base;             // wave-uniform, > 0
        const int iters = (cnt < 16) ? cnt : 16;
        int sA = 0; float pA = 0.0f;
        if (el < cnt) {                        // phase A: 16 edges x 4 heads
            sA = esrc[ebase + base + el];
            const float a = a_src[sA * 4 + hl] + adh;
            const float e = (a > 0.0f) ? a : NEG * a;
            pA = __expf(e);
        }
#pragma unroll
        for (int jb = 0; jb < 16; jb += 4) {   // uniform 4 iterations, unrolled
            const int j = jb + q;              // this quarter's edge slot (<=15)
            const int s = __shfl(sA, j << 2);
            const float p = __shfl(pA, (j << 2) | head);
            if (j < iters) {                   // divergent guard: no cross-lane ops inside
                ssum += p;
                const unsigned ho = ((unsigned)s << 8) + c0;
                const uint4 hv0 = *(const uint4*)(h1 + ho);
                const uint4 hv1 = *(const uint4*)(h1 + ho + 8);
                acc[0]  += p * bflo(hv0.x); acc[1]  += p * bfhi(hv0.x);
                acc[2]  += p * bflo(hv0.y); acc[3]  += p * bfhi(hv0.y);
                acc[4]  += p * bflo(hv0.z); acc[5]  += p * bfhi(hv0.z);
                acc[6]  += p * bflo(hv0.w); acc[7]  += p * bfhi(hv0.w);
                acc[8]  += p * bflo(hv1.x); acc[9]  += p * bfhi(hv1.x);
                acc[10] += p * bflo(hv1.y); acc[11] += p * bfhi(hv1.y);
                acc[12] += p * bflo(hv1.z); acc[13] += p * bfhi(hv1.z);
                acc[14] += p * bflo(hv1.w); acc[15] += p * bfhi(hv1.w);
            }
        }
    }
    // merge quarters (lanes with same sl share channel set; quarter bits = 4,5)
    ssum += __shfl_xor(ssum, 16); ssum += __shfl_xor(ssum, 32);
#pragma unroll
    for (int c = 0; c < 16; ++c) {
        acc[c] += __shfl_xor(acc[c], 16);
        acc[c] += __shfl_xor(acc[c], 32);
    }
    const float inv = 1.0f / ssum;
    float p0 = 0.0f, p1 = 0.0f;
#pragma unroll
    for (int c = 0; c < 16; ++c) {
        const float v = fmaxf(acc[c] * inv + b1[c0 + c], 0.0f);
        p0 += v * W2[(c0 + c) * 2 + 0];
        p1 += v * W2[(c0 + c) * 2 + 1];
    }
    if (q) { p0 = 0.0f; p1 = 0.0f; }
#pragma unroll
    for (int off = 32; off; off >>= 1) {
        p0 += __shfl_down(p0, off);
        p1 += __shfl_down(p1, off);
    }
    if (l == 0) {
        const float as2v = p0 * att_s2[0] + p1 * att_s2[1];
        const float ad2v = p0 * att_d2[0] + p1 * att_d2[1];
        node2[n] = make_float4(p0, p1, as2v, ad2v);
    }
}

// ---------------- layer-2 aggregation + log_softmax (16 lanes per node) -----
__global__ __launch_bounds__(256) void k_l2agg(const float4* __restrict__ node2,
                                               const int* __restrict__ deg,
                                               const int* __restrict__ esrc,
                                               const float* __restrict__ b2,
                                               float* __restrict__ out) {
    const int t = threadIdx.x;
    const int l = t & 63;
    const int g = l >> 4;                       // node within wave (0..3)
    const int i = l & 15;                       // lane within node group
    const int n = blockIdx.x * 16 + (t >> 6) * 4 + g;
    const int dg = deg[n];
    const int ebase = n << 6;
    const float adst = node2[n].w;
    float ssum = 0.0f, a0 = 0.0f, a1 = 0.0f;
    for (int idx = i; idx < dg; idx += 16) {
        const int s = esrc[ebase + idx];
        const float4 r = node2[s];
        const float a = r.z + adst;
        const float e = (a > 0.0f) ? a : NEG * a;
        const float p = __expf(e);
        ssum += p; a0 += p * r.x; a1 += p * r.y;
    }
#pragma unroll
    for (int off = 8; off; off >>= 1) {         // reduce within 16-lane group
        ssum += __shfl_xor(ssum, off);
        a0 += __shfl_xor(a0, off);
        a1 += __shfl_xor(a1, off);
    }
    if (i == 0) {
        const float inv = 1.0f / ssum;
        const float z0 = a0 * inv + b2[0];
        const float z1 = a1 * inv + b2[1];
        const float mz = fmaxf(z0, z1);
        const float lse = mz + __logf(__expf(z0 - mz) + __expf(z1 - mz));
        out[n * 2 + 0] = z0 - lse;
        out[n * 2 + 1] = z1 - lse;
    }
}

extern "C" void kernel_launch(void* const* d_in, const int* in_sizes, int n_in,
                              void* d_out, int out_size, void* d_ws, size_t ws_size,
                              hipStream_t stream) {
    const float* x    = (const float*)d_in[0];
    const int*   src  = (const int*)d_in[1];
    const int*   dst  = (const int*)d_in[2];
    const float* W1   = (const float*)d_in[3];
    const float* as1w = (const float*)d_in[4];
    const float* ad1w = (const float*)d_in[5];
    const float* b1   = (const float*)d_in[6];
    const float* W2   = (const float*)d_in[7];
    const float* as2w = (const float*)d_in[8];
    const float* ad2w = (const float*)d_in[9];
    const float* b2   = (const float*)d_in[10];
    float* out = (float*)d_out;

    char* w = (char*)d_ws;
    unsigned short* h1  = (unsigned short*)w; w += (size_t)NN * 256 * 2;  // 51.2 MB
    unsigned short* Wt  = (unsigned short*)w; w += (size_t)256 * KP * 2;  // 98 KB
    float* a_src = (float*)w; w += (size_t)NN * 4 * 4;
    float* a_dst = (float*)w; w += (size_t)NN * 4 * 4;
    float4* node2 = (float4*)w; w += (size_t)NN * 4 * 4;
    int* deg     = (int*)w;   w += (size_t)NN * 4;
    int* esrc    = (int*)w;   w += (size_t)NN * SLOTS * 4;                // 25.6 MB

    k_prep<<<512, 256, 0, stream>>>(W1, Wt, deg, esrc);
    k_hsgemm<<<HS_BLKS + GEMM_BLKS, 256, 0, stream>>>(src, dst, x, Wt, as1w, ad1w,
                                                      deg, esrc, h1, a_src, a_dst);
    k_l1agg<<<NN / 4, 256, 0, stream>>>(h1, a_src, a_dst, deg, esrc, b1, W2, as2w, ad2w, node2);
    k_l2agg<<<NN / 16, 256, 0, stream>>>(node2, deg, esrc, b2, out);
}

// Round 10
// 411.406 us; speedup vs baseline: 2.4880x; 1.0318x over previous
//
#include <hip/hip_runtime.h>
#include <math.h>

#define NN 100000
#define NE 1600000
#define ET (NE + NN)            // 1,700,000 edges incl. self-loops
#define NEG 0.2f
#define KP 192                  // padded K for MFMA (165 -> 192)
#define GEMM_BLKS (NN / 32)     // 3125
#define SLOTS 64                // fixed edge slots per node (P(deg>63) ~ 1e-25)
#define NPART 8                 // dst-range partitions (R6 histscat)
#define PART_SZ (NN / NPART)    // 12500
#define NCHUNK 1024
#define CH ((NE + NCHUNK - 1) / NCHUNK)   // 1563 edges per chunk
#define HS_BLKS (NPART * NCHUNK)          // 8192 histscat role blocks
#define LDA 200                 // LDS A-tile row stride in bf16 (400B rows)

typedef __attribute__((ext_vector_type(8))) short short8;
typedef __attribute__((ext_vector_type(4))) float floatx4;

// bf16 helpers (round-to-nearest-even)
__device__ __forceinline__ unsigned short f2bf(float f) {
    unsigned u = __float_as_uint(f);
    unsigned r = u + 0x7fffu + ((u >> 16) & 1u);
    return (unsigned short)(r >> 16);
}
__device__ __forceinline__ float bflo(unsigned x) { return __uint_as_float(x << 16); }
__device__ __forceinline__ float bfhi(unsigned x) { return __uint_as_float(x & 0xFFFF0000u); }

// ---------------- prep: Wt bf16 [256][KP], deg=1 + self-loop slot0 -----------
__global__ __launch_bounds__(256) void k_prep(const float* __restrict__ W,
                                              unsigned short* __restrict__ Wt,
                                              int* __restrict__ deg,
                                              int* __restrict__ esrc) {
    const int gid = blockIdx.x * 256 + threadIdx.x;
    const int G = gridDim.x * 256;
    for (int idx = gid; idx < 256 * KP; idx += G) {
        const int n = idx / KP, k = idx - n * KP;
        Wt[idx] = (k < 165) ? f2bf(W[k * 256 + n]) : (unsigned short)0;
    }
    // self-loop pre-placed at slot 0: removes 100K edges from the scatter
    for (int i = gid; i < NN; i += G) { deg[i] = 1; esrc[i << 6] = i; }
}

// ---------------- fused histscat + GEMM1 (block-role split) ------------------
// R9 counters: VGPR=64 -> 41% occupancy for the WHOLE kernel; the scatter role
// is occupancy-scaled (latency pipeline: 120us @74% in R5; 182 @41% here).
// R10: cut gemm role to ~50 VGPR (bfv[4] batch -> single bf per nn; acc[2][4]
// kept) + __launch_bounds__(256,5) to pin ~5 waves/SIMD (~62%). gemm loses a
// little ILP (~30us role, hidden under the scatter long pole anyway).
// R8 lesson: NOT cooperative; oversubscribed block churn is the TLP resource.
__global__ __launch_bounds__(256, 5) void k_hsgemm(const int* __restrict__ src,
                                                const int* __restrict__ dst,
                                                const float* __restrict__ x,
                                                const unsigned short* __restrict__ Wt,
                                                const float* __restrict__ att_s,
                                                const float* __restrict__ att_d,
                                                int* __restrict__ deg,
                                                int* __restrict__ esrc,
                                                unsigned short* __restrict__ h1,
                                                float* __restrict__ a_src,
                                                float* __restrict__ a_dst) {
    __shared__ __align__(16) unsigned lds_u32[32 * 132];   // 16.9 KB, dual-use
    const int t = threadIdx.x;
    const int b = blockIdx.x;

    if (b < HS_BLKS) {
        // ---- histscat role (R6 dst-range partitioned) ----
        const int p = b & 7;
        const int chunk = b >> 3;
        const int e0 = chunk * CH;
        const int e1 = (e0 + CH < NE) ? e0 + CH : NE;
        const int plo = p * PART_SZ, phi = plo + PART_SZ;
        for (int e = e0 + t; e < e1; e += 256) {
            const int d = dst[e];
            if (d >= plo && d < phi) {
                const int s = src[e];
                const int r = atomicAdd(&deg[d], 1);
                if (r < SLOTS) esrc[(d << 6) + r] = s;
            }
        }
        return;
    }

    // ---- gemm role: one 32-node tile ----
    const int n0 = (b - HS_BLKS) * 32;
    unsigned short* lds_a = (unsigned short*)lds_u32;      // [32][LDA] bf16 A-tile

    // stage x rows (coalesced, convert once) + zero the K-pad
    for (int i = t; i < 32 * 165; i += 256) {
        const int n = i / 165, k = i - n * 165;
        lds_a[n * LDA + k] = f2bf(x[(size_t)(n0 + n) * 165 + k]);
    }
    for (int i = t; i < 32 * (LDA - 165); i += 256) {      // k = 165..LDA-1 -> 0
        const int n = i / (LDA - 165), k = 165 + (i - n * (LDA - 165));
        lds_a[n * LDA + k] = 0;
    }
    __syncthreads();

    const int lane = t & 63, hd = t >> 6;
    const int r16 = lane & 15, quad = lane >> 4;
    floatx4 zero4 = {0.0f, 0.0f, 0.0f, 0.0f};
    floatx4 acc[2][4];
#pragma unroll
    for (int mm = 0; mm < 2; ++mm)
#pragma unroll
        for (int nn = 0; nn < 4; ++nn) acc[mm][nn] = zero4;

    const unsigned short* ar0 = lds_a + r16 * LDA;
    const unsigned short* ar1 = lds_a + (16 + r16) * LDA;
#pragma unroll
    for (int ks = 0; ks < 6; ++ks) {
        const int kb = ks * 32 + quad * 8;
        short8 a0 = *(const short8*)(ar0 + kb);
        short8 a1 = *(const short8*)(ar1 + kb);
#pragma unroll
        for (int nn = 0; nn < 4; ++nn) {       // single B-frag live (VGPR diet)
            short8 bf = *(const short8*)(Wt + (size_t)(hd * 64 + nn * 16 + r16) * KP + kb);
            acc[0][nn] = __builtin_amdgcn_mfma_f32_16x16x32_bf16(a0, bf, acc[0][nn], 0, 0, 0);
            acc[1][nn] = __builtin_amdgcn_mfma_f32_16x16x32_bf16(a1, bf, acc[1][nn], 0, 0, 0);
        }
    }

    float asw[4], adw[4];
#pragma unroll
    for (int nn = 0; nn < 4; ++nn) {
        asw[nn] = att_s[hd * 64 + nn * 16 + r16];
        adw[nn] = att_d[hd * 64 + nn * 16 + r16];
    }
#pragma unroll
    for (int mm = 0; mm < 2; ++mm)
#pragma unroll
        for (int r = 0; r < 4; ++r) {
            float ps = acc[mm][0][r] * asw[0] + acc[mm][1][r] * asw[1] +
                       acc[mm][2][r] * asw[2] + acc[mm][3][r] * asw[3];
            float pd = acc[mm][0][r] * adw[0] + acc[mm][1][r] * adw[1] +
                       acc[mm][2][r] * adw[2] + acc[mm][3][r] * adw[3];
            ps += __shfl_xor(ps, 1); ps += __shfl_xor(ps, 2);
            ps += __shfl_xor(ps, 4); ps += __shfl_xor(ps, 8);
            pd += __shfl_xor(pd, 1); pd += __shfl_xor(pd, 2);
            pd += __shfl_xor(pd, 4); pd += __shfl_xor(pd, 8);
            if (r16 == 0) {
                const int node = n0 + mm * 16 + quad * 4 + r;
                a_src[node * 4 + hd] = ps;
                a_dst[node * 4 + hd] = pd;
            }
        }

    __syncthreads();   // A-tile reads done; reuse lds_u32 for epilogue transpose
#pragma unroll
    for (int mm = 0; mm < 2; ++mm)
#pragma unroll
        for (int nn = 0; nn < 4; ++nn)
#pragma unroll
            for (int r = 0; r < 4; ++r) {
                const float v = acc[mm][nn][r];
                const float o = __shfl_xor(v, 1);
                if ((lane & 1) == 0) {
                    const unsigned pk = (unsigned)f2bf(v) | ((unsigned)f2bf(o) << 16);
                    lds_u32[(mm * 16 + quad * 4 + r) * 132 + hd * 32 + nn * 8 + (r16 >> 1)] = pk;
                }
            }
    __syncthreads();
    {
        const int row = t & 31, seg = t >> 5;
        const unsigned* p = &lds_u32[row * 132 + seg * 16];
        uint4 d0 = *(const uint4*)(p);
        uint4 d1 = *(const uint4*)(p + 4);
        uint4 d2 = *(const uint4*)(p + 8);
        uint4 d3 = *(const uint4*)(p + 12);
        unsigned short* hp = h1 + (size_t)(n0 + row) * 256 + seg * 32;
        *(uint4*)(hp) = d0;
        *(uint4*)(hp + 8) = d1;
        *(uint4*)(hp + 16) = d2;
        *(uint4*)(hp + 24) = d3;
    }
}

// ---------------- layer-1 aggregation ---------------------------------------
// wave per node; padded 64-slot edge table (beg = n<<6, cnt = deg[n]).
// NOTE (R1/R2 lessons): this 32-VGPR guarded schedule is a measured local
// optimum. Hand-batched gathers (+24 VGPR) -> occupancy 78->40%, slower.
// Unguarded loads + __launch_bounds__(256,8) -> acc[] spill (555 MB scratch
// writes), 2x slower. TLP is doing the latency hiding; leave the guard alone.
// R5: 4-way grid split costs ~45us -> single launch. R8: cooperative mega-
// kernel (capped resident grid) -> 2.8x slower; keep standalone.
__global__ __launch_bounds__(256) void k_l1agg(const unsigned short* __restrict__ h1,
                                               const float* __restrict__ a_src,
                                               const float* __restrict__ a_dst,
                                               const int* __restrict__ deg,
                                               const int* __restrict__ esrc,
                                               const float* __restrict__ b1,
                                               const float* __restrict__ W2,
                                               const float* __restrict__ att_s2,
                                               const float* __restrict__ att_d2,
                                               float4* __restrict__ node2) {
    const int t = threadIdx.x;
    const int n = blockIdx.x * 4 + (t >> 6);
    const int l = t & 63;
    const int q = l >> 4;       // quarter 0..3 (phase B)
    const int sl = l & 15;      // lane in quarter
    const int head = sl >> 2;
    const int c0 = sl * 16;
    const int el = l >> 2;      // phase-A edge slot 0..15
    const int hl = l & 3;       // phase-A head
    const int dg = deg[n];
    const int ebase = n << 6;
    const float4 ad4 = *(const float4*)&a_dst[n * 4];
    const float adh = (hl == 0) ? ad4.x : (hl == 1) ? ad4.y : (hl == 2) ? ad4.z : ad4.w;

    float ssum = 0.0f;
    float acc[16];
#pragma unroll
    for (int c = 0; c < 16; ++c) acc[c] = 0.0f;

    for (int base = 0; base < dg; base += 16) {
        const int cnt = dg - base;             // wave-uniform, > 0
        const int iters = (cnt < 16) ? cnt : 16;
        int sA = 0; float pA = 0.0f;
        if (el < cnt) {                        // phase A: 16 edges x 4 heads
            sA = esrc[ebase + base + el];
            const float a = a_src[sA * 4 + hl] + adh;
            const float e = (a > 0.0f) ? a : NEG * a;
            pA = __expf(e);
        }
#pragma unroll
        for (int jb = 0; jb < 16; jb += 4) {   // uniform 4 iterations, unrolled
            const int j = jb + q;              // this quarter's edge slot (<=15)
            const int s = __shfl(sA, j << 2);
            const float p = __shfl(pA, (j << 2) | head);
            if (j < iters) {                   // divergent guard: no cross-lane ops inside
                ssum += p;
                const unsigned ho = ((unsigned)s << 8) + c0;
                const uint4 hv0 = *(const uint4*)(h1 + ho);
                const uint4 hv1 = *(const uint4*)(h1 + ho + 8);
                acc[0]  += p * bflo(hv0.x); acc[1]  += p * bfhi(hv0.x);
                acc[2]  += p * bflo(hv0.y); acc[3]  += p * bfhi(hv0.y);
                acc[4]  += p * bflo(hv0.z); acc[5]  += p * bfhi(hv0.z);
                acc[6]  += p * bflo(hv0.w); acc[7]  += p * bfhi(hv0.w);
                acc[8]  += p * bflo(hv1.x); acc[9]  += p * bfhi(hv1.x);
                acc[10] += p * bflo(hv1.y); acc[11] += p * bfhi(hv1.y);
                acc[12] += p * bflo(hv1.z); acc[13] += p * bfhi(hv1.z);
                acc[14] += p * bflo(hv1.w); acc[15] += p * bfhi(hv1.w);
            }
        }
    }
    // merge quarters (lanes with same sl share channel set; quarter bits = 4,5)
    ssum += __shfl_xor(ssum, 16); ssum += __shfl_xor(ssum, 32);
#pragma unroll
    for (int c = 0; c < 16; ++c) {
        acc[c] += __shfl_xor(acc[c], 16);
        acc[c] += __shfl_xor(acc[c], 32);
    }
    const float inv = 1.0f / ssum;
    float p0 = 0.0f, p1 = 0.0f;
#pragma unroll
    for (int c = 0; c < 16; ++c) {
        const float v = fmaxf(acc[c] * inv + b1[c0 + c], 0.0f);
        p0 += v * W2[(c0 + c) * 2 + 0];
        p1 += v * W2[(c0 + c) * 2 + 1];
    }
    if (q) { p0 = 0.0f; p1 = 0.0f; }
#pragma unroll
    for (int off = 32; off; off >>= 1) {
        p0 += __shfl_down(p0, off);
        p1 += __shfl_down(p1, off);
    }
    if (l == 0) {
        const float as2v = p0 * att_s2[0] + p1 * att_s2[1];
        const float ad2v = p0 * att_d2[0] + p1 * att_d2[1];
        node2[n] = make_float4(p0, p1, as2v, ad2v);
    }
}

// ---------------- layer-2 aggregation + log_softmax (16 lanes per node) -----
__global__ __launch_bounds__(256) void k_l2agg(const float4* __restrict__ node2,
                                               const int* __restrict__ deg,
                                               const int* __restrict__ esrc,
                                               const float* __restrict__ b2,
                                               float* __restrict__ out) {
    const int t = threadIdx.x;
    const int l = t & 63;
    const int g = l >> 4;                       // node within wave (0..3)
    const int i = l & 15;                       // lane within node group
    const int n = blockIdx.x * 16 + (t >> 6) * 4 + g;
    const int dg = deg[n];
    const int ebase = n << 6;
    const float adst = node2[n].w;
    float ssum = 0.0f, a0 = 0.0f, a1 = 0.0f;
    for (int idx = i; idx < dg; idx += 16) {
        const int s = esrc[ebase + idx];
        const float4 r = node2[s];
        const float a = r.z + adst;
        const float e = (a > 0.0f) ? a : NEG * a;
        const float p = __expf(e);
        ssum += p; a0 += p * r.x; a1 += p * r.y;
    }
#pragma unroll
    for (int off = 8; off; off >>= 1) {         // reduce within 16-lane group
        ssum += __shfl_xor(ssum, off);
        a0 += __shfl_xor(a0, off);
        a1 += __shfl_xor(a1, off);
    }
    if (i == 0) {
        const float inv = 1.0f / ssum;
        const float z0 = a0 * inv + b2[0];
        const float z1 = a1 * inv + b2[1];
        const float mz = fmaxf(z0, z1);
        const float lse = mz + __logf(__expf(z0 - mz) + __expf(z1 - mz));
        out[n * 2 + 0] = z0 - lse;
        out[n * 2 + 1] = z1 - lse;
    }
}

extern "C" void kernel_launch(void* const* d_in, const int* in_sizes, int n_in,
                              void* d_out, int out_size, void* d_ws, size_t ws_size,
                              hipStream_t stream) {
    const float* x    = (const float*)d_in[0];
    const int*   src  = (const int*)d_in[1];
    const int*   dst  = (const int*)d_in[2];
    const float* W1   = (const float*)d_in[3];
    const float* as1w = (const float*)d_in[4];
    const float* ad1w = (const float*)d_in[5];
    const float* b1   = (const float*)d_in[6];
    const float* W2   = (const float*)d_in[7];
    const float* as2w = (const float*)d_in[8];
    const float* ad2w = (const float*)d_in[9];
    const float* b2   = (const float*)d_in[10];
    float* out = (float*)d_out;

    char* w = (char*)d_ws;
    unsigned short* h1  = (unsigned short*)w; w += (size_t)NN * 256 * 2;  // 51.2 MB
    unsigned short* Wt  = (unsigned short*)w; w += (size_t)256 * KP * 2;  // 98 KB
    float* a_src = (float*)w; w += (size_t)NN * 4 * 4;
    float* a_dst = (float*)w; w += (size_t)NN * 4 * 4;
    float4* node2 = (float4*)w; w += (size_t)NN * 4 * 4;
    int* deg     = (int*)w;   w += (size_t)NN * 4;
    int* esrc    = (int*)w;   w += (size_t)NN * SLOTS * 4;                // 25.6 MB

    k_prep<<<512, 256, 0, stream>>>(W1, Wt, deg, esrc);
    k_hsgemm<<<HS_BLKS + GEMM_BLKS, 256, 0, stream>>>(src, dst, x, Wt, as1w, ad1w,
                                                      deg, esrc, h1, a_src, a_dst);
    k_l1agg<<<NN / 4, 256, 0, stream>>>(h1, a_src, a_dst, deg, esrc, b1, W2, as2w, ad2w, node2);
    k_l2agg<<<NN / 16, 256, 0, stream>>>(node2, deg, esrc, b2, out);
}